// Round 3
// baseline (13064.037 us; speedup 1.0000x reference)
//
#include <hip/hip_runtime.h>
#include <cmath>

constexpr int T_STEPS = 512;
constexpr int BATCH   = 1024;
constexpr int DIM     = 128;
constexpr int LATENT  = 256;
constexpr int OUT_DIM = 64;

// grid = 256 blocks (1/CU), block = 512 threads = 8 waves.
// Each block owns 4 batch rows. Wave kg = tid>>6 owns a k-slice; thread owns
// 4 cols x 4 rows. Weights are PERSISTENT in VGPRs (loaded once):
//   Wi slice: d in [16kg,16kg+16), cols [4ct,4ct+4)  -> 16 float4 = 64 regs
//   Wh slice: k in [32kg,32kg+32), cols [4ct,4ct+4)  -> 32 float4 = 128 regs
// __launch_bounds__(512, 1): VGPR cap >= 256 under either HIP/CUDA semantics
// of the 2nd arg — round 2's (512,2) capped at 128 regs and spilled 21 GB.
__global__ __launch_bounds__(512, 1)
void rnn_fp32_persist(const float* __restrict__ x,    // [512][1024][128]
                      const float* __restrict__ h0,   // [1024][256]
                      const float* __restrict__ Wi,   // [128][256]
                      const float* __restrict__ bi,   // [256]
                      const float* __restrict__ Wh,   // [256][256]
                      const float* __restrict__ Wd,   // [256][64]
                      const float* __restrict__ bd,   // [64]
                      float* __restrict__ out)        // [1024][64]
{
    __shared__ float xs[2][DIM][4];      // x[t], [d][row], double-buffered
    __shared__ float hs[2][LATENT][4];   // h,    [k][row], double-buffered
    __shared__ float red[8][64][17];     // per-wave partials, padded (+1 f)

    const int tid = threadIdx.x;
    const int kg  = tid >> 6;            // wave id = k-group, 0..7
    const int ct  = tid & 63;            // column-thread: cols 4*ct..4*ct+3
    const int b0  = blockIdx.x << 2;     // first batch row of this block
    const int l_r = tid >> 1;            // reduce phase: latent index
    const int r0  = (tid & 1) << 1;      // reduce phase: row pair
    const float bias_l = bi[l_r];

    // ---- persistent weights -> VGPRs (once) ----
    float4 wi_r[16];
    float4 wh_r[32];
    {
        const float* wb = Wi + (size_t)(kg << 4) * LATENT + (ct << 2);
        #pragma unroll
        for (int i = 0; i < 16; ++i)
            wi_r[i] = *reinterpret_cast<const float4*>(wb + (size_t)i * LATENT);
        const float* hb = Wh + (size_t)(kg << 5) * LATENT + (ct << 2);
        #pragma unroll
        for (int i = 0; i < 32; ++i)
            wh_r[i] = *reinterpret_cast<const float4*>(hb + (size_t)i * LATENT);
    }

    // stage initial h and x(t=0)
    for (int i = tid; i < 4 * LATENT; i += 512) {
        const int r = i >> 8, k = i & 255;
        hs[0][k][r] = h0[(size_t)(b0 + r) * LATENT + k];
    }
    xs[0][tid & 127][tid >> 7] = x[(size_t)b0 * DIM + tid];

    // incremental prefetch pointer: x[t+1] element for this thread
    const float* xp = x + (size_t)BATCH * DIM + (size_t)b0 * DIM + tid;
    const float* const xp_last = x + (size_t)(T_STEPS - 1) * BATCH * DIM
                                   + (size_t)b0 * DIM + tid;

    int cur = 0;
    for (int t = 0; t < T_STEPS; ++t) {
        __syncthreads();   // xs[t&1] and hs[cur] ready

        // prefetch next step's x element (hidden under compute)
        const float xnext = *xp;
        if (xp != xp_last) xp += (size_t)BATCH * DIM;

        float acc[4][4];
        #pragma unroll
        for (int c = 0; c < 4; ++c)
            #pragma unroll
            for (int r = 0; r < 4; ++r) acc[c][r] = 0.f;

        // input-projection slice: 16 d-values, weights in regs
        #pragma unroll
        for (int dd = 0; dd < 16; ++dd) {
            const float4 x4 = *reinterpret_cast<const float4*>(&xs[t & 1][(kg << 4) + dd][0]);
            const float w[4] = {wi_r[dd].x, wi_r[dd].y, wi_r[dd].z, wi_r[dd].w};
            const float v[4] = {x4.x, x4.y, x4.z, x4.w};
            #pragma unroll
            for (int c = 0; c < 4; ++c)
                #pragma unroll
                for (int r = 0; r < 4; ++r) acc[c][r] += w[c] * v[r];
        }
        // recurrent slice: 32 k-values, weights in regs
        #pragma unroll
        for (int kk = 0; kk < 32; ++kk) {
            const float4 h4 = *reinterpret_cast<const float4*>(&hs[cur][(kg << 5) + kk][0]);
            const float w[4] = {wh_r[kk].x, wh_r[kk].y, wh_r[kk].z, wh_r[kk].w};
            const float v[4] = {h4.x, h4.y, h4.z, h4.w};
            #pragma unroll
            for (int c = 0; c < 4; ++c)
                #pragma unroll
                for (int r = 0; r < 4; ++r) acc[c][r] += w[c] * v[r];
        }

        // stage next x (other buffer; its readers finished at loop-top barrier)
        xs[(t + 1) & 1][tid & 127][tid >> 7] = xnext;

        // write partial sums — scalar stores, 17-stride => conflict-free
        #pragma unroll
        for (int c = 0; c < 4; ++c)
            #pragma unroll
            for (int r = 0; r < 4; ++r)
                red[kg][ct][(c << 2) + r] = acc[c][r];

        __syncthreads();   // red ready

        // reduce 8 partials + bias, tanh, write next h (2 outputs/thread)
        {
            float s0 = bias_l, s1 = bias_l;
            const int rr = l_r >> 2, cc = ((l_r & 3) << 2) + r0;
            #pragma unroll
            for (int g = 0; g < 8; ++g) {
                s0 += red[g][rr][cc];
                s1 += red[g][rr][cc + 1];
            }
            hs[cur ^ 1][l_r][r0]     = tanhf(s0);
            hs[cur ^ 1][l_r][r0 + 1] = tanhf(s1);
        }
        cur ^= 1;
    }

    __syncthreads();
    // decode: out = sigmoid(h_final @ Wd + bd), 4 rows x 64 cols per block
    if (tid < 256) {
        const int r = tid >> 6, o = tid & 63;
        float acc = bd[o];
        #pragma unroll 8
        for (int k = 0; k < LATENT; ++k)
            acc += hs[cur][k][r] * Wd[(size_t)k * OUT_DIM + o];
        out[(size_t)(b0 + r) * OUT_DIM + o] = 1.f / (1.f + expf(-acc));
    }
}

extern "C" void kernel_launch(void* const* d_in, const int* in_sizes, int n_in,
                              void* d_out, int out_size, void* d_ws, size_t ws_size,
                              hipStream_t stream) {
    const float* x  = (const float*)d_in[0];
    const float* h0 = (const float*)d_in[1];
    const float* Wi = (const float*)d_in[2];
    const float* bi = (const float*)d_in[3];
    const float* Wh = (const float*)d_in[4];
    const float* Wd = (const float*)d_in[5];
    const float* bd = (const float*)d_in[6];
    float* out = (float*)d_out;

    hipLaunchKernelGGL(rnn_fp32_persist, dim3(BATCH / 4), dim3(512), 0, stream,
                       x, h0, Wi, bi, Wh, Wd, bd, out);
}

// Round 4
// 13055.675 us; speedup vs baseline: 1.0006x; 1.0006x over previous
//
#include <hip/hip_runtime.h>
#include <cmath>

constexpr int T_STEPS = 512;
constexpr int BATCH   = 1024;
constexpr int DIM     = 128;
constexpr int LATENT  = 256;
constexpr int OUT_DIM = 64;

// grid = 256 blocks (1/CU), block = 512 threads = 8 waves (2/SIMD).
// Each block owns 4 batch rows. Wave kg = tid>>6 owns a k-slice; thread owns
// 4 cols x 4 rows. Weights are PERSISTENT in VGPRs (loaded once):
//   Wi slice: d in [16kg,16kg+16), cols [4ct,4ct+4)  -> 16 float4 = 64 regs
//   Wh slice: k in [32kg,32kg+32), cols [4ct,4ct+4)  -> 32 float4 = 128 regs
// Register budget: __launch_bounds__ failed to raise the 128-reg default cap
// (rounds 2&3: VGPR_Count=128, 22 GB scratch traffic). Use the backend
// attributes directly: waves_per_eu(2,2) -> budget = 512-reg pool / 2 = 256.
__global__ void
__attribute__((amdgpu_flat_work_group_size(512, 512), amdgpu_waves_per_eu(2, 2)))
rnn_fp32_persist(const float* __restrict__ x,    // [512][1024][128]
                 const float* __restrict__ h0,   // [1024][256]
                 const float* __restrict__ Wi,   // [128][256]
                 const float* __restrict__ bi,   // [256]
                 const float* __restrict__ Wh,   // [256][256]
                 const float* __restrict__ Wd,   // [256][64]
                 const float* __restrict__ bd,   // [64]
                 float* __restrict__ out)        // [1024][64]
{
    __shared__ float xs[2][DIM][4];      // x[t], [d][row], double-buffered
    __shared__ float hs[2][LATENT][4];   // h,    [k][row], double-buffered
    __shared__ float red[8][64][17];     // per-wave partials, padded (+1 f)

    const int tid = threadIdx.x;
    const int kg  = tid >> 6;            // wave id = k-group, 0..7
    const int ct  = tid & 63;            // column-thread: cols 4*ct..4*ct+3
    const int b0  = blockIdx.x << 2;     // first batch row of this block
    const int l_r = tid >> 1;            // reduce phase: latent index
    const int r0  = (tid & 1) << 1;      // reduce phase: row pair
    const float bias_l = bi[l_r];

    // ---- persistent weights -> VGPRs (once) ----
    float4 wi_r[16];
    float4 wh_r[32];
    {
        const float* wb = Wi + (size_t)(kg << 4) * LATENT + (ct << 2);
        #pragma unroll
        for (int i = 0; i < 16; ++i)
            wi_r[i] = *reinterpret_cast<const float4*>(wb + (size_t)i * LATENT);
        const float* hb = Wh + (size_t)(kg << 5) * LATENT + (ct << 2);
        #pragma unroll
        for (int i = 0; i < 32; ++i)
            wh_r[i] = *reinterpret_cast<const float4*>(hb + (size_t)i * LATENT);
    }

    // stage initial h and x(t=0)
    for (int i = tid; i < 4 * LATENT; i += 512) {
        const int r = i >> 8, k = i & 255;
        hs[0][k][r] = h0[(size_t)(b0 + r) * LATENT + k];
    }
    xs[0][tid & 127][tid >> 7] = x[(size_t)b0 * DIM + tid];

    // incremental prefetch pointer: x[t+1] element for this thread
    const float* xp = x + (size_t)BATCH * DIM + (size_t)b0 * DIM + tid;
    const float* const xp_last = x + (size_t)(T_STEPS - 1) * BATCH * DIM
                                   + (size_t)b0 * DIM + tid;

    int cur = 0;
    for (int t = 0; t < T_STEPS; ++t) {
        __syncthreads();   // xs[t&1] and hs[cur] ready

        // prefetch next step's x element (hidden under compute)
        const float xnext = *xp;
        if (xp != xp_last) xp += (size_t)BATCH * DIM;

        float acc[4][4];
        #pragma unroll
        for (int c = 0; c < 4; ++c)
            #pragma unroll
            for (int r = 0; r < 4; ++r) acc[c][r] = 0.f;

        // input-projection slice: 16 d-values, weights in regs
        #pragma unroll
        for (int dd = 0; dd < 16; ++dd) {
            const float4 x4 = *reinterpret_cast<const float4*>(&xs[t & 1][(kg << 4) + dd][0]);
            const float w[4] = {wi_r[dd].x, wi_r[dd].y, wi_r[dd].z, wi_r[dd].w};
            const float v[4] = {x4.x, x4.y, x4.z, x4.w};
            #pragma unroll
            for (int c = 0; c < 4; ++c)
                #pragma unroll
                for (int r = 0; r < 4; ++r) acc[c][r] += w[c] * v[r];
        }
        // recurrent slice: 32 k-values, weights in regs
        #pragma unroll
        for (int kk = 0; kk < 32; ++kk) {
            const float4 h4 = *reinterpret_cast<const float4*>(&hs[cur][(kg << 5) + kk][0]);
            const float w[4] = {wh_r[kk].x, wh_r[kk].y, wh_r[kk].z, wh_r[kk].w};
            const float v[4] = {h4.x, h4.y, h4.z, h4.w};
            #pragma unroll
            for (int c = 0; c < 4; ++c)
                #pragma unroll
                for (int r = 0; r < 4; ++r) acc[c][r] += w[c] * v[r];
        }

        // stage next x (other buffer; its readers finished at loop-top barrier)
        xs[(t + 1) & 1][tid & 127][tid >> 7] = xnext;

        // write partial sums — scalar stores, 17-stride => conflict-free
        #pragma unroll
        for (int c = 0; c < 4; ++c)
            #pragma unroll
            for (int r = 0; r < 4; ++r)
                red[kg][ct][(c << 2) + r] = acc[c][r];

        __syncthreads();   // red ready

        // reduce 8 partials + bias, tanh, write next h (2 outputs/thread)
        {
            float s0 = bias_l, s1 = bias_l;
            const int rr = l_r >> 2, cc = ((l_r & 3) << 2) + r0;
            #pragma unroll
            for (int g = 0; g < 8; ++g) {
                s0 += red[g][rr][cc];
                s1 += red[g][rr][cc + 1];
            }
            hs[cur ^ 1][l_r][r0]     = tanhf(s0);
            hs[cur ^ 1][l_r][r0 + 1] = tanhf(s1);
        }
        cur ^= 1;
    }

    __syncthreads();
    // decode: out = sigmoid(h_final @ Wd + bd), 4 rows x 64 cols per block
    if (tid < 256) {
        const int r = tid >> 6, o = tid & 63;
        float acc = bd[o];
        #pragma unroll 8
        for (int k = 0; k < LATENT; ++k)
            acc += hs[cur][k][r] * Wd[(size_t)k * OUT_DIM + o];
        out[(size_t)(b0 + r) * OUT_DIM + o] = 1.f / (1.f + expf(-acc));
    }
}

extern "C" void kernel_launch(void* const* d_in, const int* in_sizes, int n_in,
                              void* d_out, int out_size, void* d_ws, size_t ws_size,
                              hipStream_t stream) {
    const float* x  = (const float*)d_in[0];
    const float* h0 = (const float*)d_in[1];
    const float* Wi = (const float*)d_in[2];
    const float* bi = (const float*)d_in[3];
    const float* Wh = (const float*)d_in[4];
    const float* Wd = (const float*)d_in[5];
    const float* bd = (const float*)d_in[6];
    float* out = (float*)d_out;

    hipLaunchKernelGGL(rnn_fp32_persist, dim3(BATCH / 4), dim3(512), 0, stream,
                       x, h0, Wi, bi, Wh, Wd, bd, out);
}

// Round 5
// 615.395 us; speedup vs baseline: 21.2287x; 21.2151x over previous
//
#include <hip/hip_runtime.h>
#include <cmath>
#include <cstdint>

constexpr int T_STEPS = 512;
constexpr int BATCH   = 1024;
constexpr int DIM     = 128;
constexpr int LATENT  = 256;
constexpr int OUT_DIM = 64;
constexpr int ROWS    = 16;               // batch rows per block
constexpr int K_TOT   = LATENT + DIM;     // 384 = h(256) ++ x(128)
constexpr int NKSUB   = K_TOT / 8;        // 48 subtiles of 8 k-elems

typedef __attribute__((ext_vector_type(8))) short bf16x8;   // MFMA A/B frag
typedef __attribute__((ext_vector_type(4))) float f32x4;    // MFMA C/D frag

// f32 -> bf16 (RNE), self-contained (no header-version dependence)
__device__ __forceinline__ uint32_t f2bf(float f) {
    uint32_t u = __builtin_bit_cast(uint32_t, f);
    return (u + 0x7FFFu + ((u >> 16) & 1u)) >> 16;
}
__device__ __forceinline__ float bf2f(uint32_t b) {
    return __builtin_bit_cast(float, b << 16);
}

// grid = 64 blocks (16 batch rows each), block = 1024 threads = 16 waves.
// A-operand LDS layout: [ksub][row][j] (u16), ksub=k/8, j=k%8 -> a wave's
// A-frag read for one MFMA is 64 lanes x 16B contiguous = conflict-free.
// B (weights) live in 12 named bf16x8 frags per lane (48 VGPRs, no arrays).
__global__ __launch_bounds__(1024)
void rnn_mfma(const float* __restrict__ x,    // [512][1024][128]
              const float* __restrict__ h0,   // [1024][256]
              const float* __restrict__ Wi,   // [128][256]
              const float* __restrict__ bi,   // [256]
              const float* __restrict__ Wh,   // [256][256]
              const float* __restrict__ Wd,   // [256][64]
              const float* __restrict__ bd,   // [64]
              float* __restrict__ out)        // [1024][64]
{
    __shared__ uint16_t als[2][NKSUB * 128];  // 2 x 12 KiB, double-buffered A

    const int tid   = threadIdx.x;
    const int lane  = tid & 63;
    const int wv    = tid >> 6;              // wave id 0..15 -> col tile 16*wv
    const int b0    = blockIdx.x * ROWS;

    const int col   = (wv << 4) + (lane & 15);  // output latent col
    const int kgrp  = lane >> 4;                // 0..3 (k-group within frag)
    const int row16 = lane & 15;                // A row for this lane

    // ---- persistent B fragments: B[k][col], k = KK*32 + kgrp*8 + j ----
    // KK 0..7 -> Wh (k<256), KK 8..11 -> Wi (k-256), both row-stride 256.
#define LOADB(NAME, P, STRIDE)                                              \
    bf16x8 NAME; {                                                          \
        const float* _p = (P);                                              \
        NAME[0] = (short)f2bf(_p[0]);                                       \
        NAME[1] = (short)f2bf(_p[1 * (STRIDE)]);                            \
        NAME[2] = (short)f2bf(_p[2 * (STRIDE)]);                            \
        NAME[3] = (short)f2bf(_p[3 * (STRIDE)]);                            \
        NAME[4] = (short)f2bf(_p[4 * (STRIDE)]);                            \
        NAME[5] = (short)f2bf(_p[5 * (STRIDE)]);                            \
        NAME[6] = (short)f2bf(_p[6 * (STRIDE)]);                            \
        NAME[7] = (short)f2bf(_p[7 * (STRIDE)]);                            \
    }
#define WH_P(KK) (Wh + (size_t)((KK) * 32 + kgrp * 8) * LATENT + col)
#define WI_P(KK) (Wi + (size_t)((KK) * 32 - LATENT + kgrp * 8) * LATENT + col)
    LOADB(B0, WH_P(0), LATENT)  LOADB(B1, WH_P(1), LATENT)
    LOADB(B2, WH_P(2), LATENT)  LOADB(B3, WH_P(3), LATENT)
    LOADB(B4, WH_P(4), LATENT)  LOADB(B5, WH_P(5), LATENT)
    LOADB(B6, WH_P(6), LATENT)  LOADB(B7, WH_P(7), LATENT)
    LOADB(B8, WI_P(8), LATENT)  LOADB(B9, WI_P(9), LATENT)
    LOADB(B10, WI_P(10), LATENT) LOADB(B11, WI_P(11), LATENT)

    const float cb = bi[col];    // bias, same for all 4 C rows of this lane

    // ---- prologue: stage h0 and x(t=0) into als[0] ----
    {
        const int r = tid & 15;
        const int q = tid >> 4;          // 0..63
        const int c0 = q << 2;           // 4 h-cols
        float4 hv = *reinterpret_cast<const float4*>(
            &h0[(size_t)(b0 + r) * LATENT + c0]);
        const int hb = ((c0 >> 3) * 16 + r) * 8 + (c0 & 7);
        *reinterpret_cast<uint32_t*>(&als[0][hb])     = f2bf(hv.x) | (f2bf(hv.y) << 16);
        *reinterpret_cast<uint32_t*>(&als[0][hb + 2]) = f2bf(hv.z) | (f2bf(hv.w) << 16);
        const int d0 = q << 1;           // 2 x-dims
        float2 xv = *reinterpret_cast<const float2*>(
            &x[(size_t)(b0 + r) * DIM + d0]);
        const int xb = (((d0 >> 3) + 32) * 16 + r) * 8 + (d0 & 7);
        *reinterpret_cast<uint32_t*>(&als[0][xb]) = f2bf(xv.x) | (f2bf(xv.y) << 16);
    }
    __syncthreads();

    // per-lane constant offsets
    const int aoff = kgrp * 128 + row16 * 8;            // A-frag base (u16 idx)
    const int hwb  = (col >> 3) * 128 + (col & 7);      // h writeback base
    const int pr   = tid & 15, pq = tid >> 4;           // x-stage mapping
    const int xwb  = (((pq >> 2) + 32) * 16 + pr) * 8 + ((pq << 1) & 7);
    const float* xp = x + ((size_t)BATCH + b0 + pr) * DIM + (pq << 1);  // t=1

    int cur = 0;
    for (int t = 0; t < T_STEPS; ++t) {
        // prefetch x[t+1] early (hides HBM latency under MFMA chain)
        const bool pf = (t + 1 < T_STEPS);
        float2 xv = {0.f, 0.f};
        if (pf) xv = *reinterpret_cast<const float2*>(xp);
        xp += (size_t)BATCH * DIM;

        f32x4 c = {cb, cb, cb, cb};
        const uint16_t* ab = &als[cur][aoff];
#define STEPK(KK, BN) {                                                     \
        bf16x8 a = *reinterpret_cast<const bf16x8*>(ab + (KK) * 512);       \
        c = __builtin_amdgcn_mfma_f32_16x16x32_bf16(a, BN, c, 0, 0, 0); }
        STEPK(0, B0)  STEPK(1, B1)  STEPK(2, B2)  STEPK(3, B3)
        STEPK(4, B4)  STEPK(5, B5)  STEPK(6, B6)  STEPK(7, B7)
        STEPK(8, B8)  STEPK(9, B9)  STEPK(10, B10) STEPK(11, B11)

        const int nxt = cur ^ 1;
        // h_{t+1} = tanh(c) -> bf16 -> als[nxt] h-region (4 rows, same col)
        uint16_t* hw = &als[nxt][hwb];
        #pragma unroll
        for (int r = 0; r < 4; ++r)
            hw[(kgrp * 4 + r) * 8] = (uint16_t)f2bf(tanhf(c[r]));

        // x_{t+1} -> als[nxt] x-region (2-way bank aliasing = free)
        if (pf)
            *reinterpret_cast<uint32_t*>(&als[nxt][xwb]) =
                f2bf(xv.x) | (f2bf(xv.y) << 16);

        __syncthreads();
        cur = nxt;
    }

    // ---- decode: out = sigmoid(h_final @ Wd + bd), 1 output/thread ----
    {
        const int r = tid >> 6;          // 0..15
        const int o = tid & 63;
        float s = bd[o];
        const uint16_t* hb = &als[cur][r * 8];
        const float* wd = Wd + o;
        #pragma unroll 8
        for (int k = 0; k < LATENT; k += 2) {
            const uint32_t p2 = *reinterpret_cast<const uint32_t*>(
                &hb[(k >> 3) * 128 + (k & 7)]);
            s += bf2f(p2 & 0xFFFFu) * wd[(size_t)k * OUT_DIM];
            s += bf2f(p2 >> 16)     * wd[(size_t)(k + 1) * OUT_DIM];
        }
        out[(size_t)(b0 + r) * OUT_DIM + o] = 1.0f / (1.0f + expf(-s));
    }
}

extern "C" void kernel_launch(void* const* d_in, const int* in_sizes, int n_in,
                              void* d_out, int out_size, void* d_ws, size_t ws_size,
                              hipStream_t stream) {
    const float* x  = (const float*)d_in[0];
    const float* h0 = (const float*)d_in[1];
    const float* Wi = (const float*)d_in[2];
    const float* bi = (const float*)d_in[3];
    const float* Wh = (const float*)d_in[4];
    const float* Wd = (const float*)d_in[5];
    const float* bd = (const float*)d_in[6];
    float* out = (float*)d_out;

    hipLaunchKernelGGL(rnn_mfma, dim3(BATCH / ROWS), dim3(1024), 0, stream,
                       x, h0, Wi, bi, Wh, Wd, bd, out);
}